// Round 14
// baseline (375.330 us; speedup 1.0000x reference)
//
#include <hip/hip_runtime.h>
#include <math.h>

typedef unsigned int u32;
typedef unsigned long long u64;

#define BATCH 2
#define CH 128
#define NPTS 8192
#define KNB 16
#define GRP 8
#define EPSN 1e-5f

// ---- workspace layout (bytes), total ~10.8 MB ----
#define WS_A     0           // 8*128 f32   A' = s_g * (we_w1 @ pe_w2)
#define WS_PW1   4096        // 128 float4  folded pe_w1 + pe_bn (sx,sy,sz,bias)
#define WS_WE2   6144        // 64 f32      we_w2
#define WS_PTS   8192        // 16384 float4 {x,y,z,|p|^2}
#define WS_EQ    270336      // B*N*8 f32   t_g - s_g*eq
#define WS_EK    794624      // B*N*8 f32   s_g*ek
#define WS_IDX   1318912     // B*N*16 int
#define WS_VFT   2367488     // B*N*128 f32 v transposed (point-major)

__device__ __forceinline__ float d2f(float4 a, float4 b){
  #pragma clang fp contract(off)
  float dot = a.x*b.x + a.y*b.y + a.z*b.z;
  return (a.w + b.w) - 2.0f*dot;
}
__device__ __forceinline__ u64 shfl_xor_u64(u64 v, int m){
  int lo = __shfl_xor((int)(u32)v, m);
  int hi = __shfl_xor((int)(u32)(v >> 32), m);
  return (((u64)(u32)hi) << 32) | (u32)lo;
}
__device__ __forceinline__ u32 mono32(float d2){
  u32 db = __float_as_uint(d2);
  return (db & 0x80000000u) ? ~db : (db | 0x80000000u);  // monotone float->uint
}

// ---------------- K0: tiny precompute ----------------
__global__ __launch_bounds__(256) void k0_precomp(
    const float* we_w1, const float* pe_w2, const float* pe_w1,
    const float* we_g, const float* we_v,
    const float* pe_g, const float* pe_b, const float* pe_m, const float* pe_v,
    const float* we_w2, float* wsA, float4* wsPW1, float* wsWE2){
  int t = threadIdx.x;
  for (int i = t; i < 1024; i += 256){
    int g = i >> 7, h = i & 127;
    float s = 0.f;
    for (int c = 0; c < 128; ++c) s = fmaf(we_w1[g*128+c], pe_w2[c*128+h], s);
    float sg = we_g[g] / sqrtf(we_v[g] + EPSN);
    wsA[i] = s * sg;
  }
  if (t < 128){
    float s = pe_g[t] / sqrtf(pe_v[t] + EPSN);
    float bb = pe_b[t] - pe_m[t] * s;
    wsPW1[t] = make_float4(s*pe_w1[t*3+0], s*pe_w1[t*3+1], s*pe_w1[t*3+2], bb);
  }
  if (t < 64) wsWE2[t] = we_w2[t];
}

// ---------------- K1: points + squared norms ----------------
__global__ __launch_bounds__(256) void k1_pts(const float* xyz, float4* pts){
  int id = blockIdx.x*256 + threadIdx.x;
  if (id >= BATCH*NPTS) return;
  int b = id >> 13, n = id & (NPTS-1);
  float x = xyz[(b*3+0)*NPTS + n];
  float y = xyz[(b*3+1)*NPTS + n];
  float z = xyz[(b*3+2)*NPTS + n];
  float sq;
  {
    #pragma clang fp contract(off)
    sq = (x*x + y*y) + z*z;
  }
  pts[id] = make_float4(x, y, z, sq);
}

// ---------------- K2: projections, mat-split grid, 32-pt tiles ----------------
#define K2PTS 32
__global__ __launch_bounds__(256) void k2_proj(
    const float* x, const float* wq, const float* wk, const float* wv,
    const float* bnq_g, const float* bnq_b, const float* bnq_m, const float* bnq_v,
    const float* bnk_g, const float* bnk_b, const float* bnk_m, const float* bnk_v,
    const float* we_w1,
    const float* we_g, const float* we_b, const float* we_m, const float* we_v,
    float* eqT, float* ekT, float* vfT){
  __shared__ __align__(16) float qk2[K2PTS][129];  // [point][channel], 16.5 KB
  __shared__ float bnS[128], bnB[128];
  int t = threadIdx.x;
  int mat = blockIdx.x % 3;
  int tmp = blockIdx.x / 3;
  int b   = tmp / (NPTS/K2PTS);
  int n0  = (tmp % (NPTS/K2PTS)) * K2PTS;
  int p = t & 31, og = t >> 5;          // og in 0..7, 16 output channels each
  const float* xp = x + (size_t)b*CH*NPTS + n0 + p;
  const float* W = (mat == 0) ? wq : ((mat == 1) ? wk : wv);
  if (mat < 2 && t < 128){
    const float* g_ = mat==0 ? bnq_g : bnk_g;
    const float* b_ = mat==0 ? bnq_b : bnk_b;
    const float* m_ = mat==0 ? bnq_m : bnk_m;
    const float* v_ = mat==0 ? bnq_v : bnk_v;
    float s = g_[t] / sqrtf(v_[t] + EPSN);
    bnS[t] = s;
    bnB[t] = b_[t] - m_[t] * s;
  }
  __syncthreads();
  float acc[16];
  #pragma unroll
  for (int ii = 0; ii < 16; ++ii) acc[ii] = 0.f;
  for (int dd = 0; dd < 32; ++dd){
    float x0 = xp[(size_t)(4*dd+0)*NPTS];
    float x1 = xp[(size_t)(4*dd+1)*NPTS];
    float x2 = xp[(size_t)(4*dd+2)*NPTS];
    float x3 = xp[(size_t)(4*dd+3)*NPTS];
    #pragma unroll
    for (int ii = 0; ii < 16; ++ii){
      int o = og*16 + ii;
      float4 wu = *(const float4*)&W[o*128 + 4*dd];
      acc[ii] = fmaf(wu.x, x0, acc[ii]);
      acc[ii] = fmaf(wu.y, x1, acc[ii]);
      acc[ii] = fmaf(wu.z, x2, acc[ii]);
      acc[ii] = fmaf(wu.w, x3, acc[ii]);
    }
  }
  #pragma unroll
  for (int ii = 0; ii < 16; ++ii){
    int o = og*16 + ii;
    float v = acc[ii];
    if (mat < 2) v = fmaxf(fmaf(bnS[o], v, bnB[o]), 0.f);
    qk2[p][o] = v;
  }
  __syncthreads();
  if (mat < 2){
    int g = t >> 5, pp = t & 31;
    float sg = we_g[g] / sqrtf(we_v[g] + EPSN);
    float tg = we_b[g] - we_m[g] * sg;
    float s = 0.f;
    for (int c4 = 0; c4 < 32; ++c4){
      float4 wv4 = *(const float4*)&we_w1[g*128 + 4*c4];
      float4 qv4 = *(const float4*)&qk2[pp][4*c4];
      s = fmaf(wv4.x, qv4.x, s);
      s = fmaf(wv4.y, qv4.y, s);
      s = fmaf(wv4.z, qv4.z, s);
      s = fmaf(wv4.w, qv4.w, s);
    }
    float val = (mat == 0) ? (tg - sg*s) : (sg*s);
    float* dst = (mat == 0) ? eqT : ekT;
    dst[(b*NPTS + n0 + pp)*8 + g] = val;
  } else {
    #pragma unroll
    for (int i = 0; i < 4; ++i){
      int f = t + 256*i;        // 0..1023 float4 units (32 pts x 32 float4)
      int pp = f >> 5, c4 = (f & 31)*4;
      float4 v = *(const float4*)&qk2[pp][c4];
      *(float4*)&vfT[((size_t)b*NPTS + n0 + pp)*CH + c4] = v;
    }
  }
}

// ---------------- K3: exact KNN, tight threshold + lane-private slots ----------------
// T' = 0.5*Tguar (E[cnt]~45; count ~ T^1.5 locally). On underflow, fall back to
// Tguar which PROVABLY yields cnt>=16 (16 sampled full-set members <= Tguar).
// Accepts land in lane-private LDS slots (5/query/lane) -> common path has NO
// ballot/popc/mbcnt/compaction: d2f + cmp + rare divergent store. Extraction is
// order-agnostic (lexicographic (d2,idx) keys), so buffer order is irrelevant.
// Deterministic: candidate m is always handled by lane m&63, pos sequential.
#define QW   2     // queries per wave
#define QPB  8     // queries per block (4 waves x 2)
#define SLOT 5     // lane-private slots per query
__global__ __launch_bounds__(256) void k3_knn(const float4* pts, int* idxout){
  __shared__ u64 smBuf[4][QW][64][SLOT];   // 20 KB, rows private per (wave,query,lane)
  int t = threadIdx.x;
  int wv = t >> 6, lane = t & 63;
  int b  = blockIdx.x / (NPTS/QPB);
  int q0 = (blockIdx.x % (NPTS/QPB)) * QPB + wv*QW;
  const float4* P = pts + b*NPTS;

  // clear own slots (give-up-path safety)
  #pragma unroll
  for (int i = 0; i < QW; ++i)
    #pragma unroll
    for (int s = 0; s < SLOT; ++s) smBuf[wv][i][lane][s] = ~0ull;

  float4 qp0 = P[q0], qp1 = P[q0 + 1];

  // ---- sample phase: lane-min over 16 samples, 16 interleaved wave-min pops ----
  float Tg0, Tg1;
  {
    float v0 = 3.402823466e38f, v1 = 3.402823466e38f;
    #pragma unroll
    for (int j = 0; j < 16; ++j){
      float4 c = P[lane + 64*j];
      v0 = fminf(v0, d2f(qp0, c));
      v1 = fminf(v1, d2f(qp1, c));
    }
    float t0 = v0, t1 = v1;
    #pragma unroll
    for (int r = 0; r < 16; ++r){
      float m0 = v0, m1 = v1;
      #pragma unroll
      for (int msk = 1; msk <= 32; msk <<= 1){
        m0 = fminf(m0, __shfl_xor(m0, msk));
        m1 = fminf(m1, __shfl_xor(m1, msk));
      }
      if (v0 == m0) v0 = 3.402823466e38f;  // pop (bias up = safe)
      if (v1 == m1) v1 = 3.402823466e38f;
      t0 = m0; t1 = m1;
    }
    Tg0 = t0; Tg1 = t1;
  }
  // tight thresholds; sign-safe: Tg<=0 -> T'>=Tg keeps the >=16 guarantee
  float T0 = 0.5f*Tg0, T1 = 0.5f*Tg1;
  float Tlo0 = -3.0e38f, Thi0 = 3.0e38f, Tlo1 = -3.0e38f, Thi1 = 3.0e38f;
  int c0 = 0, c1 = 0;   // per-lane accept counts (count ALL accepts, store first SLOT)

  bool anybad = true;
  for (int att = 0; att < 16 && anybad; ++att){
    c0 = 0; c1 = 0;
    float4 ch0 = P[lane], ch1 = P[64 + lane], ch2 = P[128 + lane], ch3 = P[192 + lane];
    for (int base = 0; base < NPTS; base += 256){
      float4 e0 = ch0, e1 = ch1, e2 = ch2, e3 = ch3;
      int nb = base + 256;
      if (nb < NPTS){                     // prefetch next chunk over this one's compute
        ch0 = P[nb       + lane];
        ch1 = P[nb +  64 + lane];
        ch2 = P[nb + 128 + lane];
        ch3 = P[nb + 192 + lane];
      }
      auto stp = [&](float4 e, u32 m){
        float d0 = d2f(qp0, e);
        if (d0 <= T0){
          if (c0 < SLOT) smBuf[wv][0][lane][c0] = (((u64)mono32(d0)) << 32) | m;
          ++c0;
        }
        float d1 = d2f(qp1, e);
        if (d1 <= T1){
          if (c1 < SLOT) smBuf[wv][1][lane][c1] = (((u64)mono32(d1)) << 32) | m;
          ++c1;
        }
      };
      stp(e0, (u32)(base       + lane));
      stp(e1, (u32)(base +  64 + lane));
      stp(e2, (u32)(base + 128 + lane));
      stp(e3, (u32)(base + 192 + lane));
    }
    // per-query overflow flags + capped totals (exact when no overflow)
    u64 of0 = __ballot(c0 > SLOT);
    u64 of1 = __ballot(c1 > SLOT);
    int pk = (c0 < SLOT ? c0 : SLOT) | ((c1 < SLOT ? c1 : SLOT) << 16);
    #pragma unroll
    for (int msk = 1; msk <= 32; msk <<= 1) pk += __shfl_xor(pk, msk);
    int tot0 = pk & 0xFFFF, tot1 = pk >> 16;
    anybad = false;
    if (of0){
      Thi0 = T0;
      T0 = (Tlo0 > -3.0e38f) ? 0.5f*(Tlo0 + Thi0)
                             : ((T0 > 0.f) ? T0*0.5f : T0*2.0f - 1.0f);
      anybad = true;
    } else if (tot0 < 16){
      Tlo0 = T0;
      T0 = (Thi0 < 3.0e38f) ? 0.5f*(Tlo0 + Thi0) : Tg0;   // guaranteed fallback
      anybad = true;
    }
    if (of1){
      Thi1 = T1;
      T1 = (Tlo1 > -3.0e38f) ? 0.5f*(Tlo1 + Thi1)
                             : ((T1 > 0.f) ? T1*0.5f : T1*2.0f - 1.0f);
      anybad = true;
    } else if (tot1 < 16){
      Tlo1 = T1;
      T1 = (Thi1 < 3.0e38f) ? 0.5f*(Tlo1 + Thi1) : Tg1;   // guaranteed fallback
      anybad = true;
    }
  }

  // ---- extraction: register-resident, both queries' pop chains interleaved ----
  {
    int cq0 = c0 < SLOT ? c0 : SLOT;
    int cq1 = c1 < SLOT ? c1 : SLOT;
    u64 a0, a1, a2, a3, a4, b0, b1, b2, b3, b4;
    a0 = (0 < cq0) ? smBuf[wv][0][lane][0] : ~0ull;
    a1 = (1 < cq0) ? smBuf[wv][0][lane][1] : ~0ull;
    a2 = (2 < cq0) ? smBuf[wv][0][lane][2] : ~0ull;
    a3 = (3 < cq0) ? smBuf[wv][0][lane][3] : ~0ull;
    a4 = (4 < cq0) ? smBuf[wv][0][lane][4] : ~0ull;
    b0 = (0 < cq1) ? smBuf[wv][1][lane][0] : ~0ull;
    b1 = (1 < cq1) ? smBuf[wv][1][lane][1] : ~0ull;
    b2 = (2 < cq1) ? smBuf[wv][1][lane][2] : ~0ull;
    b3 = (3 < cq1) ? smBuf[wv][1][lane][3] : ~0ull;
    b4 = (4 < cq1) ? smBuf[wv][1][lane][4] : ~0ull;
    #define CE_(x,y) { if (y < x){ u64 tm_ = x; x = y; y = tm_; } }
    CE_(a0,a1) CE_(a1,a2) CE_(a2,a3) CE_(a3,a4)
    CE_(a0,a1) CE_(a1,a2) CE_(a2,a3)
    CE_(a0,a1) CE_(a1,a2)
    CE_(a0,a1)
    CE_(b0,b1) CE_(b1,b2) CE_(b2,b3) CE_(b3,b4)
    CE_(b0,b1) CE_(b1,b2) CE_(b2,b3)
    CE_(b0,b1) CE_(b1,b2)
    CE_(b0,b1)
    #undef CE_
    int nq0 = q0, nq1 = q0 + 1;
    #pragma unroll
    for (int r = 0; r < 16; ++r){
      u64 g0 = a0, g1 = b0;
      #pragma unroll
      for (int msk = 1; msk <= 32; msk <<= 1){
        u64 o0 = shfl_xor_u64(g0, msk);
        u64 o1 = shfl_xor_u64(g1, msk);
        g0 = (o0 < g0) ? o0 : g0;
        g1 = (o1 < g1) ? o1 : g1;
      }
      if (a0 == g0){ a0 = a1; a1 = a2; a2 = a3; a3 = a4; a4 = ~0ull; }
      if (b0 == g1){ b0 = b1; b1 = b2; b2 = b3; b3 = b4; b4 = ~0ull; }
      if (lane == 0){
        idxout[(b*NPTS + nq0)*16 + r] = (g0 == ~0ull) ? nq0 : (int)(g0 & (u32)(NPTS-1));
        idxout[(b*NPTS + nq1)*16 + r] = (g1 == ~0ull) ? nq1 : (int)(g1 & (u32)(NPTS-1));
      }
    }
  }
}

// ---------------- K4: fused attention, 1 wave/point, low-LDS ----------------
// __launch_bounds__(256,4): cap VGPR at 128 so occupancy isn't register-bound.
#define H2S 136
__global__ __launch_bounds__(256, 4) void k4_attn(
    const float4* pts, const float* eqT, const float* ekT, const int* idxw,
    const float* vfT, const float* wsA, const float4* wsPW1, const float* wsWE2,
    const float* pe_w2, const float* wo,
    const float* bno_g, const float* bno_b, const float* bno_m, const float* bno_v,
    float* out){
  __shared__ __align__(16) float4 smW1[128];      // 2 KB
  __shared__ __align__(16) float4 smP[4][16];     // 1 KB  r-vectors per wave
  __shared__ int   smJ[4][16];                    // 256 B neighbor indices
  __shared__ float smw[4][16][8];                 // 2 KB  weights [k][g]
  __shared__ __align__(16) float smH[4][8][H2S];  // 17.4 KB
  __shared__ __align__(16) float smOutv[4][128];  // 2 KB
  int t = threadIdx.x;
  int wv = t >> 6, lane = t & 63;
  int b  = blockIdx.x >> 11;          // NPTS/4 = 2048 blocks per batch
  int n0 = (blockIdx.x & 2047) * 4;
  if (t < 128) smW1[t] = wsPW1[t];
  __syncthreads();

  int n = n0 + wv;
  int gq = b*NPTS + n;
  int k = lane >> 2, q = lane & 3;

  // ---- phase A (wave-local): logits + softmax weights ----
  {
    float4 pn  = pts[gq];
    float4 eqa = *(const float4*)&eqT[gq*8];
    float4 eqb = *(const float4*)&eqT[gq*8+4];
    int j = idxw[gq*16 + k] & (NPTS-1);
    int gj = b*NPTS + j;
    float4 pj  = pts[gj];
    float4 eka = *(const float4*)&ekT[gj*8];
    float4 ekb = *(const float4*)&ekT[gj*8+4];
    float rx = pj.x - pn.x, ry = pj.y - pn.y, rz = pj.z - pn.z;
    if (q == 0){
      smP[wv][k] = make_float4(rx, ry, rz, 0.f);
      smJ[wv][k] = j;
    }
    // ee added ONCE after the q-lane reduction
    float ee[8] = {eka.x+eqa.x, eka.y+eqa.y, eka.z+eqa.z, eka.w+eqa.w,
                   ekb.x+eqb.x, ekb.y+eqb.y, ekb.z+eqb.z, ekb.w+eqb.w};
    float lp[8] = {0.f,0.f,0.f,0.f,0.f,0.f,0.f,0.f};
    #pragma unroll
    for (int i = 0; i < 8; ++i){
      int hb = 4*q + 16*i;
      float4 w1;
      w1 = smW1[hb+0]; float hv0 = fmaxf(fmaf(w1.x, rx, fmaf(w1.y, ry, fmaf(w1.z, rz, w1.w))), 0.f);
      w1 = smW1[hb+1]; float hv1 = fmaxf(fmaf(w1.x, rx, fmaf(w1.y, ry, fmaf(w1.z, rz, w1.w))), 0.f);
      w1 = smW1[hb+2]; float hv2 = fmaxf(fmaf(w1.x, rx, fmaf(w1.y, ry, fmaf(w1.z, rz, w1.w))), 0.f);
      w1 = smW1[hb+3]; float hv3 = fmaxf(fmaf(w1.x, rx, fmaf(w1.y, ry, fmaf(w1.z, rz, w1.w))), 0.f);
      #pragma unroll
      for (int g = 0; g < 8; ++g){
        float4 a4 = *(const float4*)&wsA[g*128 + hb];
        lp[g] = fmaf(a4.x, hv0, lp[g]);
        lp[g] = fmaf(a4.y, hv1, lp[g]);
        lp[g] = fmaf(a4.z, hv2, lp[g]);
        lp[g] = fmaf(a4.w, hv3, lp[g]);
      }
    }
    #pragma unroll
    for (int g = 0; g < 8; ++g){
      lp[g] += __shfl_xor(lp[g], 1);
      lp[g] += __shfl_xor(lp[g], 2);
      lp[g] = fmaxf(lp[g] + ee[g], 0.f);
    }
    float lo0 = 0.f, lo1 = 0.f;
    #pragma unroll
    for (int g = 0; g < 8; ++g){
      lo0 = fmaf(wsWE2[(2*q+0)*8 + g], lp[g], lo0);
      lo1 = fmaf(wsWE2[(2*q+1)*8 + g], lp[g], lo1);
    }
    float m0 = lo0, m1 = lo1;
    #pragma unroll
    for (int msk = 4; msk <= 32; msk <<= 1){
      m0 = fmaxf(m0, __shfl_xor(m0, msk));
      m1 = fmaxf(m1, __shfl_xor(m1, msk));
    }
    float e0 = __expf(lo0 - m0), e1 = __expf(lo1 - m1);
    float s0 = e0, s1 = e1;
    #pragma unroll
    for (int msk = 4; msk <= 32; msk <<= 1){
      s0 += __shfl_xor(s0, msk);
      s1 += __shfl_xor(s1, msk);
    }
    smw[wv][k][2*q+0] = e0 / s0;
    smw[wv][k][2*q+1] = e1 / s1;
  }

  // ---- phase C (wave-local): H[g][h] = sum_k w[g,k]*relu(W1[h].r_k) ----
  {
    int g3 = lane >> 3, hh = lane & 7;
    float4 H4[4];
    #pragma unroll
    for (int ii = 0; ii < 4; ++ii) H4[ii] = make_float4(0.f,0.f,0.f,0.f);
    for (int kk = 0; kk < 16; ++kk){
      float4 r4 = smP[wv][kk];
      float wg  = smw[wv][kk][g3];
      #pragma unroll
      for (int ii = 0; ii < 4; ++ii){
        int hb = 4*hh + 32*ii;
        float4 w1;
        w1 = smW1[hb+0]; float hv0 = fmaxf(fmaf(w1.x, r4.x, fmaf(w1.y, r4.y, fmaf(w1.z, r4.z, w1.w))), 0.f);
        w1 = smW1[hb+1]; float hv1 = fmaxf(fmaf(w1.x, r4.x, fmaf(w1.y, r4.y, fmaf(w1.z, r4.z, w1.w))), 0.f);
        w1 = smW1[hb+2]; float hv2 = fmaxf(fmaf(w1.x, r4.x, fmaf(w1.y, r4.y, fmaf(w1.z, r4.z, w1.w))), 0.f);
        w1 = smW1[hb+3]; float hv3 = fmaxf(fmaf(w1.x, r4.x, fmaf(w1.y, r4.y, fmaf(w1.z, r4.z, w1.w))), 0.f);
        H4[ii].x = fmaf(wg, hv0, H4[ii].x);
        H4[ii].y = fmaf(wg, hv1, H4[ii].y);
        H4[ii].z = fmaf(wg, hv2, H4[ii].z);
        H4[ii].w = fmaf(wg, hv3, H4[ii].w);
      }
    }
    #pragma unroll
    for (int ii = 0; ii < 4; ++ii)
      *(float4*)&smH[wv][g3][4*hh + 32*ii] = H4[ii];
  }
  __syncthreads();   // all waves' smH/smw/smJ visible block-wide

  // ---- phase D (block-wide, t<128): outv for all 4 points; pe_w2 rows read once ----
  if (t < 128){
    int c = t, g = c >> 4;
    float acc[4] = {0.f, 0.f, 0.f, 0.f};
    for (int i = 0; i < 32; ++i){
      float4 pw = *(const float4*)&pe_w2[c*128 + 4*i];
      #pragma unroll
      for (int pt = 0; pt < 4; ++pt){
        float4 h4 = *(const float4*)&smH[pt][g][4*i];
        acc[pt] = fmaf(pw.x, h4.x, acc[pt]);
        acc[pt] = fmaf(pw.y, h4.y, acc[pt]);
        acc[pt] = fmaf(pw.z, h4.z, acc[pt]);
        acc[pt] = fmaf(pw.w, h4.w, acc[pt]);
      }
    }
    #pragma unroll
    for (int pt = 0; pt < 4; ++pt){
      #pragma unroll
      for (int kk = 0; kk < 16; ++kk){
        int jj = smJ[pt][kk];
        float wgk = smw[pt][kk][g];
        acc[pt] = fmaf(wgk, vfT[((size_t)b*NPTS + jj)*CH + c], acc[pt]);
      }
      smOutv[pt][c] = acc[pt];
    }
  }
  __syncthreads();

  // ---- phase E (t<128): out[o][n0..n0+3] = bno(wo @ outv), float4 store ----
  if (t < 128){
    int o = t;
    float so = bno_g[o] / sqrtf(bno_v[o] + EPSN);
    float bo = bno_b[o] - bno_m[o] * so;
    float fa[4] = {0.f, 0.f, 0.f, 0.f};
    for (int i = 0; i < 32; ++i){
      float4 pw = *(const float4*)&wo[o*128 + 4*i];
      #pragma unroll
      for (int pt = 0; pt < 4; ++pt){
        float4 h4 = *(const float4*)&smOutv[pt][4*i];
        fa[pt] = fmaf(pw.x, h4.x, fa[pt]);
        fa[pt] = fmaf(pw.y, h4.y, fa[pt]);
        fa[pt] = fmaf(pw.z, h4.z, fa[pt]);
        fa[pt] = fmaf(pw.w, h4.w, fa[pt]);
      }
    }
    float4 st;
    st.x = fmaf(so, fa[0], bo);
    st.y = fmaf(so, fa[1], bo);
    st.z = fmaf(so, fa[2], bo);
    st.w = fmaf(so, fa[3], bo);
    *(float4*)&out[((size_t)b*CH + o)*NPTS + n0] = st;
  }
}

extern "C" void kernel_launch(void* const* d_in, const int* in_sizes, int n_in,
                              void* d_out, int out_size, void* d_ws, size_t ws_size,
                              hipStream_t stream){
  const float* x     = (const float*)d_in[0];
  const float* xyz   = (const float*)d_in[1];
  const float* wq    = (const float*)d_in[2];
  const float* bnq_g = (const float*)d_in[3];
  const float* bnq_b = (const float*)d_in[4];
  const float* bnq_m = (const float*)d_in[5];
  const float* bnq_v = (const float*)d_in[6];
  const float* wk    = (const float*)d_in[7];
  const float* bnk_g = (const float*)d_in[8];
  const float* bnk_b = (const float*)d_in[9];
  const float* bnk_m = (const float*)d_in[10];
  const float* bnk_v = (const float*)d_in[11];
  const float* wv    = (const float*)d_in[12];
  const float* pe_w1 = (const float*)d_in[13];
  const float* pe_g  = (const float*)d_in[14];
  const float* pe_b  = (const float*)d_in[15];
  const float* pe_m  = (const float*)d_in[16];
  const float* pe_v  = (const float*)d_in[17];
  const float* pe_w2 = (const float*)d_in[18];
  const float* we_w1 = (const float*)d_in[19];
  const float* we_g  = (const float*)d_in[20];
  const float* we_b  = (const float*)d_in[21];
  const float* we_m  = (const float*)d_in[22];
  const float* we_v  = (const float*)d_in[23];
  const float* we_w2 = (const float*)d_in[24];
  const float* wo    = (const float*)d_in[25];
  const float* bno_g = (const float*)d_in[26];
  const float* bno_b = (const float*)d_in[27];
  const float* bno_m = (const float*)d_in[28];
  const float* bno_v = (const float*)d_in[29];

  char* ws = (char*)d_ws;
  float*  wsA   = (float*)(ws + WS_A);
  float4* wsPW1 = (float4*)(ws + WS_PW1);
  float*  wsWE2 = (float*)(ws + WS_WE2);
  float4* pts   = (float4*)(ws + WS_PTS);
  float*  eqT   = (float*)(ws + WS_EQ);
  float*  ekT   = (float*)(ws + WS_EK);
  int*    idxw  = (int*)(ws + WS_IDX);
  float*  vfT   = (float*)(ws + WS_VFT);
  float*  outp  = (float*)d_out;

  k0_precomp<<<dim3(1), dim3(256), 0, stream>>>(we_w1, pe_w2, pe_w1, we_g, we_v,
                                                pe_g, pe_b, pe_m, pe_v, we_w2,
                                                wsA, wsPW1, wsWE2);
  k1_pts<<<dim3(64), dim3(256), 0, stream>>>(xyz, pts);
  k2_proj<<<dim3(BATCH*(NPTS/K2PTS)*3), dim3(256), 0, stream>>>(x, wq, wk, wv,
                                               bnq_g, bnq_b, bnq_m, bnq_v,
                                               bnk_g, bnk_b, bnk_m, bnk_v,
                                               we_w1, we_g, we_b, we_m, we_v,
                                               eqT, ekT, vfT);
  k3_knn<<<dim3(BATCH*(NPTS/QPB)), dim3(256), 0, stream>>>(pts, idxw);
  k4_attn<<<dim3(BATCH*(NPTS/4)), dim3(256), 0, stream>>>(pts, eqT, ekT, idxw, vfT,
                                                wsA, wsPW1, wsWE2, pe_w2, wo,
                                                bno_g, bno_b, bno_m, bno_v, outp);
}

// Round 15
// 351.213 us; speedup vs baseline: 1.0687x; 1.0687x over previous
//
#include <hip/hip_runtime.h>
#include <math.h>

typedef unsigned int u32;
typedef unsigned long long u64;

#define BATCH 2
#define CH 128
#define NPTS 8192
#define KNB 16
#define GRP 8
#define EPSN 1e-5f

// ---- workspace layout (bytes), total ~10.8 MB ----
#define WS_A     0           // 8*128 f32   A' = s_g * (we_w1 @ pe_w2)
#define WS_PW1   4096        // 128 float4  folded pe_w1 + pe_bn (sx,sy,sz,bias)
#define WS_WE2   6144        // 64 f32      we_w2
#define WS_PTS   8192        // 16384 float4 {x,y,z,|p|^2}
#define WS_EQ    270336      // B*N*8 f32   t_g - s_g*eq
#define WS_EK    794624      // B*N*8 f32   s_g*ek
#define WS_IDX   1318912     // B*N*16 int
#define WS_VFT   2367488     // B*N*128 f32 v transposed (point-major)

__device__ __forceinline__ float d2f(float4 a, float4 b){
  #pragma clang fp contract(off)
  float dot = a.x*b.x + a.y*b.y + a.z*b.z;
  return (a.w + b.w) - 2.0f*dot;
}
__device__ __forceinline__ u64 shfl_xor_u64(u64 v, int m){
  int lo = __shfl_xor((int)(u32)v, m);
  int hi = __shfl_xor((int)(u32)(v >> 32), m);
  return (((u64)(u32)hi) << 32) | (u32)lo;
}
__device__ __forceinline__ int mbcnt64(u64 bm){
  return (int)__builtin_amdgcn_mbcnt_hi((u32)(bm >> 32),
          __builtin_amdgcn_mbcnt_lo((u32)(bm & 0xFFFFFFFFull), 0u));
}
__device__ __forceinline__ u32 mono32(float d2){
  u32 db = __float_as_uint(d2);
  return (db & 0x80000000u) ? ~db : (db | 0x80000000u);  // monotone float->uint
}

// ---------------- K0: tiny precompute ----------------
__global__ __launch_bounds__(256) void k0_precomp(
    const float* we_w1, const float* pe_w2, const float* pe_w1,
    const float* we_g, const float* we_v,
    const float* pe_g, const float* pe_b, const float* pe_m, const float* pe_v,
    const float* we_w2, float* wsA, float4* wsPW1, float* wsWE2){
  int t = threadIdx.x;
  for (int i = t; i < 1024; i += 256){
    int g = i >> 7, h = i & 127;
    float s = 0.f;
    for (int c = 0; c < 128; ++c) s = fmaf(we_w1[g*128+c], pe_w2[c*128+h], s);
    float sg = we_g[g] / sqrtf(we_v[g] + EPSN);
    wsA[i] = s * sg;
  }
  if (t < 128){
    float s = pe_g[t] / sqrtf(pe_v[t] + EPSN);
    float bb = pe_b[t] - pe_m[t] * s;
    wsPW1[t] = make_float4(s*pe_w1[t*3+0], s*pe_w1[t*3+1], s*pe_w1[t*3+2], bb);
  }
  if (t < 64) wsWE2[t] = we_w2[t];
}

// ---------------- K1: points + squared norms ----------------
__global__ __launch_bounds__(256) void k1_pts(const float* xyz, float4* pts){
  int id = blockIdx.x*256 + threadIdx.x;
  if (id >= BATCH*NPTS) return;
  int b = id >> 13, n = id & (NPTS-1);
  float x = xyz[(b*3+0)*NPTS + n];
  float y = xyz[(b*3+1)*NPTS + n];
  float z = xyz[(b*3+2)*NPTS + n];
  float sq;
  {
    #pragma clang fp contract(off)
    sq = (x*x + y*y) + z*z;
  }
  pts[id] = make_float4(x, y, z, sq);
}

// ---------------- K2: projections, mat-split grid, 32-pt tiles ----------------
#define K2PTS 32
__global__ __launch_bounds__(256) void k2_proj(
    const float* x, const float* wq, const float* wk, const float* wv,
    const float* bnq_g, const float* bnq_b, const float* bnq_m, const float* bnq_v,
    const float* bnk_g, const float* bnk_b, const float* bnk_m, const float* bnk_v,
    const float* we_w1,
    const float* we_g, const float* we_b, const float* we_m, const float* we_v,
    float* eqT, float* ekT, float* vfT){
  __shared__ __align__(16) float qk2[K2PTS][129];  // [point][channel], 16.5 KB
  __shared__ float bnS[128], bnB[128];
  int t = threadIdx.x;
  int mat = blockIdx.x % 3;
  int tmp = blockIdx.x / 3;
  int b   = tmp / (NPTS/K2PTS);
  int n0  = (tmp % (NPTS/K2PTS)) * K2PTS;
  int p = t & 31, og = t >> 5;          // og in 0..7, 16 output channels each
  const float* xp = x + (size_t)b*CH*NPTS + n0 + p;
  const float* W = (mat == 0) ? wq : ((mat == 1) ? wk : wv);
  if (mat < 2 && t < 128){
    const float* g_ = mat==0 ? bnq_g : bnk_g;
    const float* b_ = mat==0 ? bnq_b : bnk_b;
    const float* m_ = mat==0 ? bnq_m : bnk_m;
    const float* v_ = mat==0 ? bnq_v : bnk_v;
    float s = g_[t] / sqrtf(v_[t] + EPSN);
    bnS[t] = s;
    bnB[t] = b_[t] - m_[t] * s;
  }
  __syncthreads();
  float acc[16];
  #pragma unroll
  for (int ii = 0; ii < 16; ++ii) acc[ii] = 0.f;
  for (int dd = 0; dd < 32; ++dd){
    float x0 = xp[(size_t)(4*dd+0)*NPTS];
    float x1 = xp[(size_t)(4*dd+1)*NPTS];
    float x2 = xp[(size_t)(4*dd+2)*NPTS];
    float x3 = xp[(size_t)(4*dd+3)*NPTS];
    #pragma unroll
    for (int ii = 0; ii < 16; ++ii){
      int o = og*16 + ii;
      float4 wu = *(const float4*)&W[o*128 + 4*dd];
      acc[ii] = fmaf(wu.x, x0, acc[ii]);
      acc[ii] = fmaf(wu.y, x1, acc[ii]);
      acc[ii] = fmaf(wu.z, x2, acc[ii]);
      acc[ii] = fmaf(wu.w, x3, acc[ii]);
    }
  }
  #pragma unroll
  for (int ii = 0; ii < 16; ++ii){
    int o = og*16 + ii;
    float v = acc[ii];
    if (mat < 2) v = fmaxf(fmaf(bnS[o], v, bnB[o]), 0.f);
    qk2[p][o] = v;
  }
  __syncthreads();
  if (mat < 2){
    int g = t >> 5, pp = t & 31;
    float sg = we_g[g] / sqrtf(we_v[g] + EPSN);
    float tg = we_b[g] - we_m[g] * sg;
    float s = 0.f;
    for (int c4 = 0; c4 < 32; ++c4){
      float4 wv4 = *(const float4*)&we_w1[g*128 + 4*c4];
      float4 qv4 = *(const float4*)&qk2[pp][4*c4];
      s = fmaf(wv4.x, qv4.x, s);
      s = fmaf(wv4.y, qv4.y, s);
      s = fmaf(wv4.z, qv4.z, s);
      s = fmaf(wv4.w, qv4.w, s);
    }
    float val = (mat == 0) ? (tg - sg*s) : (sg*s);
    float* dst = (mat == 0) ? eqT : ekT;
    dst[(b*NPTS + n0 + pp)*8 + g] = val;
  } else {
    #pragma unroll
    for (int i = 0; i < 4; ++i){
      int f = t + 256*i;        // 0..1023 float4 units (32 pts x 32 float4)
      int pp = f >> 5, c4 = (f & 31)*4;
      float4 v = *(const float4*)&qk2[pp][c4];
      *(float4*)&vfT[((size_t)b*NPTS + n0 + pp)*CH + c4] = v;
    }
  }
}

// ---------------- K3: exact KNN, round-13 logic, 1-wave blocks ----------------
// Same verified algorithm as round 13 (lane-min sampled T with guaranteed
// cnt>=16, ballot compaction, bisect-on-overflow, prefetched chunks,
// interleaved reductions, register-resident extraction). Geometry change only:
// block = 64 threads (1 wave), grid = 8192 -> 32 resident blocks/CU with 4
// scheduling rounds, so fast waves are backfilled and retry-tail waves no
// longer strand a whole 4-wave block (round-13's tail: occupancy 38%).
#define QW   2     // queries per wave
#define CAPQ 288   // candidate slots per query
__global__ __launch_bounds__(64) void k3_knn(const float4* pts, int* idxout){
  __shared__ u64 smBuf[QW][CAPQ];   // 4.6 KB, private to this 1-wave block
  int lane = threadIdx.x;
  int b  = blockIdx.x / (NPTS/QW);
  int q0 = (blockIdx.x % (NPTS/QW)) * QW;
  const float4* P = pts + b*NPTS;

  // clear rows (give-up-path safety); QW*CAPQ/64 = 9 slots/lane
  #pragma unroll
  for (int s = 0; s < QW*CAPQ/64; ++s){
    int f = s*64 + lane;
    smBuf[f / CAPQ][f % CAPQ] = ~0ull;
  }

  float4 qp[QW];
  #pragma unroll
  for (int i = 0; i < QW; ++i) qp[i] = P[q0 + i];

  // ---- sample phase: shared load stream, interleaved pop chains ----
  float T[QW];
  {
    float v0 = 3.402823466e38f, v1 = 3.402823466e38f;
    #pragma unroll
    for (int j = 0; j < 16; ++j){
      float4 c = P[lane + 64*j];
      v0 = fminf(v0, d2f(qp[0], c));
      v1 = fminf(v1, d2f(qp[1], c));
    }
    float t0 = v0, t1 = v1;
    #pragma unroll
    for (int r = 0; r < 16; ++r){
      float m0 = v0, m1 = v1;
      #pragma unroll
      for (int msk = 1; msk <= 32; msk <<= 1){
        m0 = fminf(m0, __shfl_xor(m0, msk));
        m1 = fminf(m1, __shfl_xor(m1, msk));
      }
      if (v0 == m0) v0 = 3.402823466e38f;  // pop (bias up = safe)
      if (v1 == m1) v1 = 3.402823466e38f;
      t0 = m0; t1 = m1;
    }
    T[0] = t0; T[1] = t1;
  }

  // ---- collect sweeps: prefetched chunks; cnt>=16 guaranteed; bisect on overflow ----
  float Tlo[QW], Thi[QW]; int cnt[QW];
  #pragma unroll
  for (int i = 0; i < QW; ++i){ Tlo[i] = -3.0e38f; Thi[i] = 3.0e38f; cnt[i] = 0; }
  auto step = [&](float4 c, u32 m, int i){
    float d2 = d2f(qp[i], c);
    bool pred = d2 <= T[i];
    u64 bm = __ballot(pred);
    if (bm){                              // wave-uniform skip of empty groups
      int cc = __popcll(bm);
      if (pred && cnt[i] + cc <= CAPQ){
        int pos = cnt[i] + mbcnt64(bm);
        smBuf[i][pos] = (((u64)mono32(d2)) << 32) | m;
      }
      cnt[i] += cc;
    }
  };
  bool anybad = true;
  for (int att = 0; att < 16 && anybad; ++att){
    #pragma unroll
    for (int i = 0; i < QW; ++i) cnt[i] = 0;
    float4 c0 = P[lane], c1 = P[64 + lane], c2 = P[128 + lane], c3 = P[192 + lane];
    for (int base = 0; base < NPTS; base += 256){
      float4 e0 = c0, e1 = c1, e2 = c2, e3 = c3;
      int nb = base + 256;
      if (nb < NPTS){                     // prefetch next chunk over this one's compute
        c0 = P[nb       + lane];
        c1 = P[nb +  64 + lane];
        c2 = P[nb + 128 + lane];
        c3 = P[nb + 192 + lane];
      }
      #pragma unroll
      for (int i = 0; i < QW; ++i){
        step(e0, (u32)(base       + lane), i);
        step(e1, (u32)(base +  64 + lane), i);
        step(e2, (u32)(base + 128 + lane), i);
        step(e3, (u32)(base + 192 + lane), i);
      }
    }
    anybad = false;
    #pragma unroll
    for (int i = 0; i < QW; ++i){
      if (cnt[i] > CAPQ){
        Thi[i] = T[i];
        T[i] = (Tlo[i] > -3.0e38f) ? 0.5f*(Tlo[i] + Thi[i])
                                   : ((T[i] > 0.f) ? T[i]*0.5f : T[i]*2.0f - 1.0f);
        anybad = true;
      } else if (cnt[i] < 16){   // only reachable after an overflow-shrink
        Tlo[i] = T[i];
        T[i] = 0.5f*(Tlo[i] + Thi[i]);
        anybad = true;
      }
    }
  }

  // ---- extraction: register-resident, both queries' pop chains interleaved ----
  {
    int cq0 = cnt[0] < CAPQ ? cnt[0] : CAPQ;
    int cq1 = cnt[1] < CAPQ ? cnt[1] : CAPQ;
    u64 a0, a1, a2, a3, a4, b0, b1, b2, b3, b4;
    a0 = (lane       < cq0) ? smBuf[0][lane      ] : ~0ull;
    a1 = (lane +  64 < cq0) ? smBuf[0][lane +  64] : ~0ull;
    a2 = (lane + 128 < cq0) ? smBuf[0][lane + 128] : ~0ull;
    a3 = (lane + 192 < cq0) ? smBuf[0][lane + 192] : ~0ull;
    a4 = (lane + 256 < cq0) ? smBuf[0][lane + 256] : ~0ull;
    b0 = (lane       < cq1) ? smBuf[1][lane      ] : ~0ull;
    b1 = (lane +  64 < cq1) ? smBuf[1][lane +  64] : ~0ull;
    b2 = (lane + 128 < cq1) ? smBuf[1][lane + 128] : ~0ull;
    b3 = (lane + 192 < cq1) ? smBuf[1][lane + 192] : ~0ull;
    b4 = (lane + 256 < cq1) ? smBuf[1][lane + 256] : ~0ull;
    #define CE_(x,y) { if (y < x){ u64 tm_ = x; x = y; y = tm_; } }
    CE_(a0,a1) CE_(a1,a2) CE_(a2,a3) CE_(a3,a4)
    CE_(a0,a1) CE_(a1,a2) CE_(a2,a3)
    CE_(a0,a1) CE_(a1,a2)
    CE_(a0,a1)
    CE_(b0,b1) CE_(b1,b2) CE_(b2,b3) CE_(b3,b4)
    CE_(b0,b1) CE_(b1,b2) CE_(b2,b3)
    CE_(b0,b1) CE_(b1,b2)
    CE_(b0,b1)
    #undef CE_
    int nq0 = q0, nq1 = q0 + 1;
    #pragma unroll
    for (int r = 0; r < 16; ++r){
      u64 g0 = a0, g1 = b0;
      #pragma unroll
      for (int msk = 1; msk <= 32; msk <<= 1){
        u64 o0 = shfl_xor_u64(g0, msk);
        u64 o1 = shfl_xor_u64(g1, msk);
        g0 = (o0 < g0) ? o0 : g0;
        g1 = (o1 < g1) ? o1 : g1;
      }
      if (a0 == g0){ a0 = a1; a1 = a2; a2 = a3; a3 = a4; a4 = ~0ull; }
      if (b0 == g1){ b0 = b1; b1 = b2; b2 = b3; b3 = b4; b4 = ~0ull; }
      if (lane == 0){
        idxout[(b*NPTS + nq0)*16 + r] = (g0 == ~0ull) ? nq0 : (int)(g0 & (u32)(NPTS-1));
        idxout[(b*NPTS + nq1)*16 + r] = (g1 == ~0ull) ? nq1 : (int)(g1 & (u32)(NPTS-1));
      }
    }
  }
}

// ---------------- K4: fused attention, 1 wave/point, low-LDS ----------------
// __launch_bounds__(256,4): cap VGPR at 128 so occupancy isn't register-bound.
#define H2S 136
__global__ __launch_bounds__(256, 4) void k4_attn(
    const float4* pts, const float* eqT, const float* ekT, const int* idxw,
    const float* vfT, const float* wsA, const float4* wsPW1, const float* wsWE2,
    const float* pe_w2, const float* wo,
    const float* bno_g, const float* bno_b, const float* bno_m, const float* bno_v,
    float* out){
  __shared__ __align__(16) float4 smW1[128];      // 2 KB
  __shared__ __align__(16) float4 smP[4][16];     // 1 KB  r-vectors per wave
  __shared__ int   smJ[4][16];                    // 256 B neighbor indices
  __shared__ float smw[4][16][8];                 // 2 KB  weights [k][g]
  __shared__ __align__(16) float smH[4][8][H2S];  // 17.4 KB
  __shared__ __align__(16) float smOutv[4][128];  // 2 KB
  int t = threadIdx.x;
  int wv = t >> 6, lane = t & 63;
  int b  = blockIdx.x >> 11;          // NPTS/4 = 2048 blocks per batch
  int n0 = (blockIdx.x & 2047) * 4;
  if (t < 128) smW1[t] = wsPW1[t];
  __syncthreads();

  int n = n0 + wv;
  int gq = b*NPTS + n;
  int k = lane >> 2, q = lane & 3;

  // ---- phase A (wave-local): logits + softmax weights ----
  {
    float4 pn  = pts[gq];
    float4 eqa = *(const float4*)&eqT[gq*8];
    float4 eqb = *(const float4*)&eqT[gq*8+4];
    int j = idxw[gq*16 + k] & (NPTS-1);
    int gj = b*NPTS + j;
    float4 pj  = pts[gj];
    float4 eka = *(const float4*)&ekT[gj*8];
    float4 ekb = *(const float4*)&ekT[gj*8+4];
    float rx = pj.x - pn.x, ry = pj.y - pn.y, rz = pj.z - pn.z;
    if (q == 0){
      smP[wv][k] = make_float4(rx, ry, rz, 0.f);
      smJ[wv][k] = j;
    }
    // ee added ONCE after the q-lane reduction
    float ee[8] = {eka.x+eqa.x, eka.y+eqa.y, eka.z+eqa.z, eka.w+eqa.w,
                   ekb.x+eqb.x, ekb.y+eqb.y, ekb.z+eqb.z, ekb.w+eqb.w};
    float lp[8] = {0.f,0.f,0.f,0.f,0.f,0.f,0.f,0.f};
    #pragma unroll
    for (int i = 0; i < 8; ++i){
      int hb = 4*q + 16*i;
      float4 w1;
      w1 = smW1[hb+0]; float hv0 = fmaxf(fmaf(w1.x, rx, fmaf(w1.y, ry, fmaf(w1.z, rz, w1.w))), 0.f);
      w1 = smW1[hb+1]; float hv1 = fmaxf(fmaf(w1.x, rx, fmaf(w1.y, ry, fmaf(w1.z, rz, w1.w))), 0.f);
      w1 = smW1[hb+2]; float hv2 = fmaxf(fmaf(w1.x, rx, fmaf(w1.y, ry, fmaf(w1.z, rz, w1.w))), 0.f);
      w1 = smW1[hb+3]; float hv3 = fmaxf(fmaf(w1.x, rx, fmaf(w1.y, ry, fmaf(w1.z, rz, w1.w))), 0.f);
      #pragma unroll
      for (int g = 0; g < 8; ++g){
        float4 a4 = *(const float4*)&wsA[g*128 + hb];
        lp[g] = fmaf(a4.x, hv0, lp[g]);
        lp[g] = fmaf(a4.y, hv1, lp[g]);
        lp[g] = fmaf(a4.z, hv2, lp[g]);
        lp[g] = fmaf(a4.w, hv3, lp[g]);
      }
    }
    #pragma unroll
    for (int g = 0; g < 8; ++g){
      lp[g] += __shfl_xor(lp[g], 1);
      lp[g] += __shfl_xor(lp[g], 2);
      lp[g] = fmaxf(lp[g] + ee[g], 0.f);
    }
    float lo0 = 0.f, lo1 = 0.f;
    #pragma unroll
    for (int g = 0; g < 8; ++g){
      lo0 = fmaf(wsWE2[(2*q+0)*8 + g], lp[g], lo0);
      lo1 = fmaf(wsWE2[(2*q+1)*8 + g], lp[g], lo1);
    }
    float m0 = lo0, m1 = lo1;
    #pragma unroll
    for (int msk = 4; msk <= 32; msk <<= 1){
      m0 = fmaxf(m0, __shfl_xor(m0, msk));
      m1 = fmaxf(m1, __shfl_xor(m1, msk));
    }
    float e0 = __expf(lo0 - m0), e1 = __expf(lo1 - m1);
    float s0 = e0, s1 = e1;
    #pragma unroll
    for (int msk = 4; msk <= 32; msk <<= 1){
      s0 += __shfl_xor(s0, msk);
      s1 += __shfl_xor(s1, msk);
    }
    smw[wv][k][2*q+0] = e0 / s0;
    smw[wv][k][2*q+1] = e1 / s1;
  }

  // ---- phase C (wave-local): H[g][h] = sum_k w[g,k]*relu(W1[h].r_k) ----
  {
    int g3 = lane >> 3, hh = lane & 7;
    float4 H4[4];
    #pragma unroll
    for (int ii = 0; ii < 4; ++ii) H4[ii] = make_float4(0.f,0.f,0.f,0.f);
    for (int kk = 0; kk < 16; ++kk){
      float4 r4 = smP[wv][kk];
      float wg  = smw[wv][kk][g3];
      #pragma unroll
      for (int ii = 0; ii < 4; ++ii){
        int hb = 4*hh + 32*ii;
        float4 w1;
        w1 = smW1[hb+0]; float hv0 = fmaxf(fmaf(w1.x, r4.x, fmaf(w1.y, r4.y, fmaf(w1.z, r4.z, w1.w))), 0.f);
        w1 = smW1[hb+1]; float hv1 = fmaxf(fmaf(w1.x, r4.x, fmaf(w1.y, r4.y, fmaf(w1.z, r4.z, w1.w))), 0.f);
        w1 = smW1[hb+2]; float hv2 = fmaxf(fmaf(w1.x, r4.x, fmaf(w1.y, r4.y, fmaf(w1.z, r4.z, w1.w))), 0.f);
        w1 = smW1[hb+3]; float hv3 = fmaxf(fmaf(w1.x, r4.x, fmaf(w1.y, r4.y, fmaf(w1.z, r4.z, w1.w))), 0.f);
        H4[ii].x = fmaf(wg, hv0, H4[ii].x);
        H4[ii].y = fmaf(wg, hv1, H4[ii].y);
        H4[ii].z = fmaf(wg, hv2, H4[ii].z);
        H4[ii].w = fmaf(wg, hv3, H4[ii].w);
      }
    }
    #pragma unroll
    for (int ii = 0; ii < 4; ++ii)
      *(float4*)&smH[wv][g3][4*hh + 32*ii] = H4[ii];
  }
  __syncthreads();   // all waves' smH/smw/smJ visible block-wide

  // ---- phase D (block-wide, t<128): outv for all 4 points; pe_w2 rows read once ----
  if (t < 128){
    int c = t, g = c >> 4;
    float acc[4] = {0.f, 0.f, 0.f, 0.f};
    for (int i = 0; i < 32; ++i){
      float4 pw = *(const float4*)&pe_w2[c*128 + 4*i];
      #pragma unroll
      for (int pt = 0; pt < 4; ++pt){
        float4 h4 = *(const float4*)&smH[pt][g][4*i];
        acc[pt] = fmaf(pw.x, h4.x, acc[pt]);
        acc[pt] = fmaf(pw.y, h4.y, acc[pt]);
        acc[pt] = fmaf(pw.z, h4.z, acc[pt]);
        acc[pt] = fmaf(pw.w, h4.w, acc[pt]);
      }
    }
    #pragma unroll
    for (int pt = 0; pt < 4; ++pt){
      #pragma unroll
      for (int kk = 0; kk < 16; ++kk){
        int jj = smJ[pt][kk];
        float wgk = smw[pt][kk][g];
        acc[pt] = fmaf(wgk, vfT[((size_t)b*NPTS + jj)*CH + c], acc[pt]);
      }
      smOutv[pt][c] = acc[pt];
    }
  }
  __syncthreads();

  // ---- phase E (t<128): out[o][n0..n0+3] = bno(wo @ outv), float4 store ----
  if (t < 128){
    int o = t;
    float so = bno_g[o] / sqrtf(bno_v[o] + EPSN);
    float bo = bno_b[o] - bno_m[o] * so;
    float fa[4] = {0.f, 0.f, 0.f, 0.f};
    for (int i = 0; i < 32; ++i){
      float4 pw = *(const float4*)&wo[o*128 + 4*i];
      #pragma unroll
      for (int pt = 0; pt < 4; ++pt){
        float4 h4 = *(const float4*)&smOutv[pt][4*i];
        fa[pt] = fmaf(pw.x, h4.x, fa[pt]);
        fa[pt] = fmaf(pw.y, h4.y, fa[pt]);
        fa[pt] = fmaf(pw.z, h4.z, fa[pt]);
        fa[pt] = fmaf(pw.w, h4.w, fa[pt]);
      }
    }
    float4 st;
    st.x = fmaf(so, fa[0], bo);
    st.y = fmaf(so, fa[1], bo);
    st.z = fmaf(so, fa[2], bo);
    st.w = fmaf(so, fa[3], bo);
    *(float4*)&out[((size_t)b*CH + o)*NPTS + n0] = st;
  }
}

extern "C" void kernel_launch(void* const* d_in, const int* in_sizes, int n_in,
                              void* d_out, int out_size, void* d_ws, size_t ws_size,
                              hipStream_t stream){
  const float* x     = (const float*)d_in[0];
  const float* xyz   = (const float*)d_in[1];
  const float* wq    = (const float*)d_in[2];
  const float* bnq_g = (const float*)d_in[3];
  const float* bnq_b = (const float*)d_in[4];
  const float* bnq_m = (const float*)d_in[5];
  const float* bnq_v = (const float*)d_in[6];
  const float* wk    = (const float*)d_in[7];
  const float* bnk_g = (const float*)d_in[8];
  const float* bnk_b = (const float*)d_in[9];
  const float* bnk_m = (const float*)d_in[10];
  const float* bnk_v = (const float*)d_in[11];
  const float* wv    = (const float*)d_in[12];
  const float* pe_w1 = (const float*)d_in[13];
  const float* pe_g  = (const float*)d_in[14];
  const float* pe_b  = (const float*)d_in[15];
  const float* pe_m  = (const float*)d_in[16];
  const float* pe_v  = (const float*)d_in[17];
  const float* pe_w2 = (const float*)d_in[18];
  const float* we_w1 = (const float*)d_in[19];
  const float* we_g  = (const float*)d_in[20];
  const float* we_b  = (const float*)d_in[21];
  const float* we_m  = (const float*)d_in[22];
  const float* we_v  = (const float*)d_in[23];
  const float* we_w2 = (const float*)d_in[24];
  const float* wo    = (const float*)d_in[25];
  const float* bno_g = (const float*)d_in[26];
  const float* bno_b = (const float*)d_in[27];
  const float* bno_m = (const float*)d_in[28];
  const float* bno_v = (const float*)d_in[29];

  char* ws = (char*)d_ws;
  float*  wsA   = (float*)(ws + WS_A);
  float4* wsPW1 = (float4*)(ws + WS_PW1);
  float*  wsWE2 = (float*)(ws + WS_WE2);
  float4* pts   = (float4*)(ws + WS_PTS);
  float*  eqT   = (float*)(ws + WS_EQ);
  float*  ekT   = (float*)(ws + WS_EK);
  int*    idxw  = (int*)(ws + WS_IDX);
  float*  vfT   = (float*)(ws + WS_VFT);
  float*  outp  = (float*)d_out;

  k0_precomp<<<dim3(1), dim3(256), 0, stream>>>(we_w1, pe_w2, pe_w1, we_g, we_v,
                                                pe_g, pe_b, pe_m, pe_v, we_w2,
                                                wsA, wsPW1, wsWE2);
  k1_pts<<<dim3(64), dim3(256), 0, stream>>>(xyz, pts);
  k2_proj<<<dim3(BATCH*(NPTS/K2PTS)*3), dim3(256), 0, stream>>>(x, wq, wk, wv,
                                               bnq_g, bnq_b, bnq_m, bnq_v,
                                               bnk_g, bnk_b, bnk_m, bnk_v,
                                               we_w1, we_g, we_b, we_m, we_v,
                                               eqT, ekT, vfT);
  k3_knn<<<dim3(BATCH*(NPTS/QW)), dim3(64), 0, stream>>>(pts, idxw);
  k4_attn<<<dim3(BATCH*(NPTS/4)), dim3(256), 0, stream>>>(pts, eqT, ekT, idxw, vfT,
                                                wsA, wsPW1, wsWE2, pe_w2, wo,
                                                bno_g, bno_b, bno_m, bno_v, outp);
}

// Round 16
// 327.691 us; speedup vs baseline: 1.1454x; 1.0718x over previous
//
#include <hip/hip_runtime.h>
#include <math.h>

typedef unsigned int u32;
typedef unsigned long long u64;

#define BATCH 2
#define CH 128
#define NPTS 8192
#define KNB 16
#define GRP 8
#define EPSN 1e-5f

// ---- workspace layout (bytes), total ~10.8 MB ----
#define WS_A     0           // 8*128 f32   A' = s_g * (we_w1 @ pe_w2)
#define WS_PW1   4096        // 128 float4  folded pe_w1 + pe_bn (sx,sy,sz,bias)
#define WS_WE2   6144        // 64 f32      we_w2
#define WS_PTS   8192        // 16384 float4 {x,y,z,|p|^2}
#define WS_EQ    270336      // B*N*8 f32   t_g - s_g*eq
#define WS_EK    794624      // B*N*8 f32   s_g*ek
#define WS_IDX   1318912     // B*N*16 int
#define WS_VFT   2367488     // B*N*128 f32 v transposed (point-major)

__device__ __forceinline__ float d2f(float4 a, float4 b){
  #pragma clang fp contract(off)
  float dot = a.x*b.x + a.y*b.y + a.z*b.z;
  return (a.w + b.w) - 2.0f*dot;
}
__device__ __forceinline__ u64 shfl_xor_u64(u64 v, int m){
  int lo = __shfl_xor((int)(u32)v, m);
  int hi = __shfl_xor((int)(u32)(v >> 32), m);
  return (((u64)(u32)hi) << 32) | (u32)lo;
}
__device__ __forceinline__ int mbcnt64(u64 bm){
  return (int)__builtin_amdgcn_mbcnt_hi((u32)(bm >> 32),
          __builtin_amdgcn_mbcnt_lo((u32)(bm & 0xFFFFFFFFull), 0u));
}
__device__ __forceinline__ u32 mono32(float d2){
  u32 db = __float_as_uint(d2);
  return (db & 0x80000000u) ? ~db : (db | 0x80000000u);  // monotone float->uint
}

// ---------------- K0: tiny precompute ----------------
__global__ __launch_bounds__(256) void k0_precomp(
    const float* we_w1, const float* pe_w2, const float* pe_w1,
    const float* we_g, const float* we_v,
    const float* pe_g, const float* pe_b, const float* pe_m, const float* pe_v,
    const float* we_w2, float* wsA, float4* wsPW1, float* wsWE2){
  int t = threadIdx.x;
  for (int i = t; i < 1024; i += 256){
    int g = i >> 7, h = i & 127;
    float s = 0.f;
    for (int c = 0; c < 128; ++c) s = fmaf(we_w1[g*128+c], pe_w2[c*128+h], s);
    float sg = we_g[g] / sqrtf(we_v[g] + EPSN);
    wsA[i] = s * sg;
  }
  if (t < 128){
    float s = pe_g[t] / sqrtf(pe_v[t] + EPSN);
    float bb = pe_b[t] - pe_m[t] * s;
    wsPW1[t] = make_float4(s*pe_w1[t*3+0], s*pe_w1[t*3+1], s*pe_w1[t*3+2], bb);
  }
  if (t < 64) wsWE2[t] = we_w2[t];
}

// ---------------- K1: points + squared norms ----------------
__global__ __launch_bounds__(256) void k1_pts(const float* xyz, float4* pts){
  int id = blockIdx.x*256 + threadIdx.x;
  if (id >= BATCH*NPTS) return;
  int b = id >> 13, n = id & (NPTS-1);
  float x = xyz[(b*3+0)*NPTS + n];
  float y = xyz[(b*3+1)*NPTS + n];
  float z = xyz[(b*3+2)*NPTS + n];
  float sq;
  {
    #pragma clang fp contract(off)
    sq = (x*x + y*y) + z*z;
  }
  pts[id] = make_float4(x, y, z, sq);
}

// ---------------- K23: fused projections (k2 role) + exact KNN (k3 role) ----------------
// k2 and k3 are data-independent; serialized they each leave ~60% of issue
// slots idle (k3: VALUBusy 65%, occ 38%; k2 memory-latency-bound). One launch,
// roles interleaved 3:4 per 7-block group; both bodies byte-identical to their
// verified standalone forms. Dynamic LDS unioned: k2 casts to qk2[32][129]+bn,
// each k3 wave takes a private 4608-B slice (no __syncthreads in k3 path;
// role branch is block-uniform so k2's __syncthreads stays legal).
#define K2PTS 32
#define QW   2     // queries per k3 wave-unit
#define CAPQ 288   // candidate slots per query
#define K23_LDS 18432
__global__ __launch_bounds__(256) void k23_fused(
    const float* x, const float* wq, const float* wk, const float* wv,
    const float* bnq_g, const float* bnq_b, const float* bnq_m, const float* bnq_v,
    const float* bnk_g, const float* bnk_b, const float* bnk_m, const float* bnk_v,
    const float* we_w1,
    const float* we_g, const float* we_b, const float* we_m, const float* we_v,
    float* eqT, float* ekT, float* vfT,
    const float4* pts, int* idxout){
  extern __shared__ __align__(16) char smRaw[];
  int t = threadIdx.x;
  int grp = blockIdx.x / 7, rem = blockIdx.x % 7;

  if (rem < 3){
    // ================= k2 role (verbatim round-11..15 k2_proj) =================
    float (*qk2)[129] = (float(*)[129])smRaw;            // 16512 B
    float* bnS = (float*)(smRaw + 16512);                // 512 B
    float* bnB = (float*)(smRaw + 17024);                // 512 B
    int bid2 = grp*3 + rem;                              // 0..1535
    int mat = bid2 % 3;
    int tmp = bid2 / 3;
    int b   = tmp / (NPTS/K2PTS);
    int n0  = (tmp % (NPTS/K2PTS)) * K2PTS;
    int p = t & 31, og = t >> 5;
    const float* xp = x + (size_t)b*CH*NPTS + n0 + p;
    const float* W = (mat == 0) ? wq : ((mat == 1) ? wk : wv);
    if (mat < 2 && t < 128){
      const float* g_ = mat==0 ? bnq_g : bnk_g;
      const float* b_ = mat==0 ? bnq_b : bnk_b;
      const float* m_ = mat==0 ? bnq_m : bnk_m;
      const float* v_ = mat==0 ? bnq_v : bnk_v;
      float s = g_[t] / sqrtf(v_[t] + EPSN);
      bnS[t] = s;
      bnB[t] = b_[t] - m_[t] * s;
    }
    __syncthreads();
    float acc[16];
    #pragma unroll
    for (int ii = 0; ii < 16; ++ii) acc[ii] = 0.f;
    for (int dd = 0; dd < 32; ++dd){
      float x0 = xp[(size_t)(4*dd+0)*NPTS];
      float x1 = xp[(size_t)(4*dd+1)*NPTS];
      float x2 = xp[(size_t)(4*dd+2)*NPTS];
      float x3 = xp[(size_t)(4*dd+3)*NPTS];
      #pragma unroll
      for (int ii = 0; ii < 16; ++ii){
        int o = og*16 + ii;
        float4 wu = *(const float4*)&W[o*128 + 4*dd];
        acc[ii] = fmaf(wu.x, x0, acc[ii]);
        acc[ii] = fmaf(wu.y, x1, acc[ii]);
        acc[ii] = fmaf(wu.z, x2, acc[ii]);
        acc[ii] = fmaf(wu.w, x3, acc[ii]);
      }
    }
    #pragma unroll
    for (int ii = 0; ii < 16; ++ii){
      int o = og*16 + ii;
      float v = acc[ii];
      if (mat < 2) v = fmaxf(fmaf(bnS[o], v, bnB[o]), 0.f);
      qk2[p][o] = v;
    }
    __syncthreads();
    if (mat < 2){
      int g = t >> 5, pp = t & 31;
      float sg = we_g[g] / sqrtf(we_v[g] + EPSN);
      float tg = we_b[g] - we_m[g] * sg;
      float s = 0.f;
      for (int c4 = 0; c4 < 32; ++c4){
        float4 wv4 = *(const float4*)&we_w1[g*128 + 4*c4];
        float4 qv4 = *(const float4*)&qk2[pp][4*c4];
        s = fmaf(wv4.x, qv4.x, s);
        s = fmaf(wv4.y, qv4.y, s);
        s = fmaf(wv4.z, qv4.z, s);
        s = fmaf(wv4.w, qv4.w, s);
      }
      float val = (mat == 0) ? (tg - sg*s) : (sg*s);
      float* dst = (mat == 0) ? eqT : ekT;
      dst[(b*NPTS + n0 + pp)*8 + g] = val;
    } else {
      #pragma unroll
      for (int i = 0; i < 4; ++i){
        int f = t + 256*i;
        int pp = f >> 5, c4 = (f & 31)*4;
        float4 v = *(const float4*)&qk2[pp][c4];
        *(float4*)&vfT[((size_t)b*NPTS + n0 + pp)*CH + c4] = v;
      }
    }
    return;
  }

  // ================= k3 role (verbatim round-15 k3_knn, 4 units/block) =================
  int wv3 = t >> 6, lane = t & 63;
  u64 (*smBuf)[CAPQ] = (u64(*)[CAPQ])(smRaw + wv3*(QW*CAPQ*8));  // 4608 B/wave
  int unit = (grp*4 + (rem - 3))*4 + wv3;                 // 0..8191
  int b  = unit / (NPTS/QW);
  int q0 = (unit % (NPTS/QW)) * QW;
  const float4* P = pts + b*NPTS;

  // clear rows (give-up-path safety); QW*CAPQ/64 = 9 slots/lane
  #pragma unroll
  for (int s = 0; s < QW*CAPQ/64; ++s){
    int f = s*64 + lane;
    smBuf[f / CAPQ][f % CAPQ] = ~0ull;
  }

  float4 qp[QW];
  #pragma unroll
  for (int i = 0; i < QW; ++i) qp[i] = P[q0 + i];

  // ---- sample phase: shared load stream, interleaved pop chains ----
  float T[QW];
  {
    float v0 = 3.402823466e38f, v1 = 3.402823466e38f;
    #pragma unroll
    for (int j = 0; j < 16; ++j){
      float4 c = P[lane + 64*j];
      v0 = fminf(v0, d2f(qp[0], c));
      v1 = fminf(v1, d2f(qp[1], c));
    }
    float t0 = v0, t1 = v1;
    #pragma unroll
    for (int r = 0; r < 16; ++r){
      float m0 = v0, m1 = v1;
      #pragma unroll
      for (int msk = 1; msk <= 32; msk <<= 1){
        m0 = fminf(m0, __shfl_xor(m0, msk));
        m1 = fminf(m1, __shfl_xor(m1, msk));
      }
      if (v0 == m0) v0 = 3.402823466e38f;  // pop (bias up = safe)
      if (v1 == m1) v1 = 3.402823466e38f;
      t0 = m0; t1 = m1;
    }
    T[0] = t0; T[1] = t1;
  }

  // ---- collect sweeps: prefetched chunks; cnt>=16 guaranteed; bisect on overflow ----
  float Tlo[QW], Thi[QW]; int cnt[QW];
  #pragma unroll
  for (int i = 0; i < QW; ++i){ Tlo[i] = -3.0e38f; Thi[i] = 3.0e38f; cnt[i] = 0; }
  auto step = [&](float4 c, u32 m, int i){
    float d2 = d2f(qp[i], c);
    bool pred = d2 <= T[i];
    u64 bm = __ballot(pred);
    if (bm){                              // wave-uniform skip of empty groups
      int cc = __popcll(bm);
      if (pred && cnt[i] + cc <= CAPQ){
        int pos = cnt[i] + mbcnt64(bm);
        smBuf[i][pos] = (((u64)mono32(d2)) << 32) | m;
      }
      cnt[i] += cc;
    }
  };
  bool anybad = true;
  for (int att = 0; att < 16 && anybad; ++att){
    #pragma unroll
    for (int i = 0; i < QW; ++i) cnt[i] = 0;
    float4 c0 = P[lane], c1 = P[64 + lane], c2 = P[128 + lane], c3 = P[192 + lane];
    for (int base = 0; base < NPTS; base += 256){
      float4 e0 = c0, e1 = c1, e2 = c2, e3 = c3;
      int nb = base + 256;
      if (nb < NPTS){                     // prefetch next chunk over this one's compute
        c0 = P[nb       + lane];
        c1 = P[nb +  64 + lane];
        c2 = P[nb + 128 + lane];
        c3 = P[nb + 192 + lane];
      }
      #pragma unroll
      for (int i = 0; i < QW; ++i){
        step(e0, (u32)(base       + lane), i);
        step(e1, (u32)(base +  64 + lane), i);
        step(e2, (u32)(base + 128 + lane), i);
        step(e3, (u32)(base + 192 + lane), i);
      }
    }
    anybad = false;
    #pragma unroll
    for (int i = 0; i < QW; ++i){
      if (cnt[i] > CAPQ){
        Thi[i] = T[i];
        T[i] = (Tlo[i] > -3.0e38f) ? 0.5f*(Tlo[i] + Thi[i])
                                   : ((T[i] > 0.f) ? T[i]*0.5f : T[i]*2.0f - 1.0f);
        anybad = true;
      } else if (cnt[i] < 16){   // only reachable after an overflow-shrink
        Tlo[i] = T[i];
        T[i] = 0.5f*(Tlo[i] + Thi[i]);
        anybad = true;
      }
    }
  }

  // ---- extraction: register-resident, both queries' pop chains interleaved ----
  {
    int cq0 = cnt[0] < CAPQ ? cnt[0] : CAPQ;
    int cq1 = cnt[1] < CAPQ ? cnt[1] : CAPQ;
    u64 a0, a1, a2, a3, a4, b0, b1, b2, b3, b4;
    a0 = (lane       < cq0) ? smBuf[0][lane      ] : ~0ull;
    a1 = (lane +  64 < cq0) ? smBuf[0][lane +  64] : ~0ull;
    a2 = (lane + 128 < cq0) ? smBuf[0][lane + 128] : ~0ull;
    a3 = (lane + 192 < cq0) ? smBuf[0][lane + 192] : ~0ull;
    a4 = (lane + 256 < cq0) ? smBuf[0][lane + 256] : ~0ull;
    b0 = (lane       < cq1) ? smBuf[1][lane      ] : ~0ull;
    b1 = (lane +  64 < cq1) ? smBuf[1][lane +  64] : ~0ull;
    b2 = (lane + 128 < cq1) ? smBuf[1][lane + 128] : ~0ull;
    b3 = (lane + 192 < cq1) ? smBuf[1][lane + 192] : ~0ull;
    b4 = (lane + 256 < cq1) ? smBuf[1][lane + 256] : ~0ull;
    #define CE_(x,y) { if (y < x){ u64 tm_ = x; x = y; y = tm_; } }
    CE_(a0,a1) CE_(a1,a2) CE_(a2,a3) CE_(a3,a4)
    CE_(a0,a1) CE_(a1,a2) CE_(a2,a3)
    CE_(a0,a1) CE_(a1,a2)
    CE_(a0,a1)
    CE_(b0,b1) CE_(b1,b2) CE_(b2,b3) CE_(b3,b4)
    CE_(b0,b1) CE_(b1,b2) CE_(b2,b3)
    CE_(b0,b1) CE_(b1,b2)
    CE_(b0,b1)
    #undef CE_
    int nq0 = q0, nq1 = q0 + 1;
    #pragma unroll
    for (int r = 0; r < 16; ++r){
      u64 g0 = a0, g1 = b0;
      #pragma unroll
      for (int msk = 1; msk <= 32; msk <<= 1){
        u64 o0 = shfl_xor_u64(g0, msk);
        u64 o1 = shfl_xor_u64(g1, msk);
        g0 = (o0 < g0) ? o0 : g0;
        g1 = (o1 < g1) ? o1 : g1;
      }
      if (a0 == g0){ a0 = a1; a1 = a2; a2 = a3; a3 = a4; a4 = ~0ull; }
      if (b0 == g1){ b0 = b1; b1 = b2; b2 = b3; b3 = b4; b4 = ~0ull; }
      if (lane == 0){
        idxout[(b*NPTS + nq0)*16 + r] = (g0 == ~0ull) ? nq0 : (int)(g0 & (u32)(NPTS-1));
        idxout[(b*NPTS + nq1)*16 + r] = (g1 == ~0ull) ? nq1 : (int)(g1 & (u32)(NPTS-1));
      }
    }
  }
}

// ---------------- K4: fused attention, 1 wave/point, low-LDS ----------------
// __launch_bounds__(256,4): cap VGPR at 128 so occupancy isn't register-bound.
#define H2S 136
__global__ __launch_bounds__(256, 4) void k4_attn(
    const float4* pts, const float* eqT, const float* ekT, const int* idxw,
    const float* vfT, const float* wsA, const float4* wsPW1, const float* wsWE2,
    const float* pe_w2, const float* wo,
    const float* bno_g, const float* bno_b, const float* bno_m, const float* bno_v,
    float* out){
  __shared__ __align__(16) float4 smW1[128];      // 2 KB
  __shared__ __align__(16) float4 smP[4][16];     // 1 KB  r-vectors per wave
  __shared__ int   smJ[4][16];                    // 256 B neighbor indices
  __shared__ float smw[4][16][8];                 // 2 KB  weights [k][g]
  __shared__ __align__(16) float smH[4][8][H2S];  // 17.4 KB
  __shared__ __align__(16) float smOutv[4][128];  // 2 KB
  int t = threadIdx.x;
  int wv = t >> 6, lane = t & 63;
  int b  = blockIdx.x >> 11;          // NPTS/4 = 2048 blocks per batch
  int n0 = (blockIdx.x & 2047) * 4;
  if (t < 128) smW1[t] = wsPW1[t];
  __syncthreads();

  int n = n0 + wv;
  int gq = b*NPTS + n;
  int k = lane >> 2, q = lane & 3;

  // ---- phase A (wave-local): logits + softmax weights ----
  {
    float4 pn  = pts[gq];
    float4 eqa = *(const float4*)&eqT[gq*8];
    float4 eqb = *(const float4*)&eqT[gq*8+4];
    int j = idxw[gq*16 + k] & (NPTS-1);
    int gj = b*NPTS + j;
    float4 pj  = pts[gj];
    float4 eka = *(const float4*)&ekT[gj*8];
    float4 ekb = *(const float4*)&ekT[gj*8+4];
    float rx = pj.x - pn.x, ry = pj.y - pn.y, rz = pj.z - pn.z;
    if (q == 0){
      smP[wv][k] = make_float4(rx, ry, rz, 0.f);
      smJ[wv][k] = j;
    }
    // ee added ONCE after the q-lane reduction
    float ee[8] = {eka.x+eqa.x, eka.y+eqa.y, eka.z+eqa.z, eka.w+eqa.w,
                   ekb.x+eqb.x, ekb.y+eqb.y, ekb.z+eqb.z, ekb.w+eqb.w};
    float lp[8] = {0.f,0.f,0.f,0.f,0.f,0.f,0.f,0.f};
    #pragma unroll
    for (int i = 0; i < 8; ++i){
      int hb = 4*q + 16*i;
      float4 w1;
      w1 = smW1[hb+0]; float hv0 = fmaxf(fmaf(w1.x, rx, fmaf(w1.y, ry, fmaf(w1.z, rz, w1.w))), 0.f);
      w1 = smW1[hb+1]; float hv1 = fmaxf(fmaf(w1.x, rx, fmaf(w1.y, ry, fmaf(w1.z, rz, w1.w))), 0.f);
      w1 = smW1[hb+2]; float hv2 = fmaxf(fmaf(w1.x, rx, fmaf(w1.y, ry, fmaf(w1.z, rz, w1.w))), 0.f);
      w1 = smW1[hb+3]; float hv3 = fmaxf(fmaf(w1.x, rx, fmaf(w1.y, ry, fmaf(w1.z, rz, w1.w))), 0.f);
      #pragma unroll
      for (int g = 0; g < 8; ++g){
        float4 a4 = *(const float4*)&wsA[g*128 + hb];
        lp[g] = fmaf(a4.x, hv0, lp[g]);
        lp[g] = fmaf(a4.y, hv1, lp[g]);
        lp[g] = fmaf(a4.z, hv2, lp[g]);
        lp[g] = fmaf(a4.w, hv3, lp[g]);
      }
    }
    #pragma unroll
    for (int g = 0; g < 8; ++g){
      lp[g] += __shfl_xor(lp[g], 1);
      lp[g] += __shfl_xor(lp[g], 2);
      lp[g] = fmaxf(lp[g] + ee[g], 0.f);
    }
    float lo0 = 0.f, lo1 = 0.f;
    #pragma unroll
    for (int g = 0; g < 8; ++g){
      lo0 = fmaf(wsWE2[(2*q+0)*8 + g], lp[g], lo0);
      lo1 = fmaf(wsWE2[(2*q+1)*8 + g], lp[g], lo1);
    }
    float m0 = lo0, m1 = lo1;
    #pragma unroll
    for (int msk = 4; msk <= 32; msk <<= 1){
      m0 = fmaxf(m0, __shfl_xor(m0, msk));
      m1 = fmaxf(m1, __shfl_xor(m1, msk));
    }
    float e0 = __expf(lo0 - m0), e1 = __expf(lo1 - m1);
    float s0 = e0, s1 = e1;
    #pragma unroll
    for (int msk = 4; msk <= 32; msk <<= 1){
      s0 += __shfl_xor(s0, msk);
      s1 += __shfl_xor(s1, msk);
    }
    smw[wv][k][2*q+0] = e0 / s0;
    smw[wv][k][2*q+1] = e1 / s1;
  }

  // ---- phase C (wave-local): H[g][h] = sum_k w[g,k]*relu(W1[h].r_k) ----
  {
    int g3 = lane >> 3, hh = lane & 7;
    float4 H4[4];
    #pragma unroll
    for (int ii = 0; ii < 4; ++ii) H4[ii] = make_float4(0.f,0.f,0.f,0.f);
    for (int kk = 0; kk < 16; ++kk){
      float4 r4 = smP[wv][kk];
      float wg  = smw[wv][kk][g3];
      #pragma unroll
      for (int ii = 0; ii < 4; ++ii){
        int hb = 4*hh + 32*ii;
        float4 w1;
        w1 = smW1[hb+0]; float hv0 = fmaxf(fmaf(w1.x, r4.x, fmaf(w1.y, r4.y, fmaf(w1.z, r4.z, w1.w))), 0.f);
        w1 = smW1[hb+1]; float hv1 = fmaxf(fmaf(w1.x, r4.x, fmaf(w1.y, r4.y, fmaf(w1.z, r4.z, w1.w))), 0.f);
        w1 = smW1[hb+2]; float hv2 = fmaxf(fmaf(w1.x, r4.x, fmaf(w1.y, r4.y, fmaf(w1.z, r4.z, w1.w))), 0.f);
        w1 = smW1[hb+3]; float hv3 = fmaxf(fmaf(w1.x, r4.x, fmaf(w1.y, r4.y, fmaf(w1.z, r4.z, w1.w))), 0.f);
        H4[ii].x = fmaf(wg, hv0, H4[ii].x);
        H4[ii].y = fmaf(wg, hv1, H4[ii].y);
        H4[ii].z = fmaf(wg, hv2, H4[ii].z);
        H4[ii].w = fmaf(wg, hv3, H4[ii].w);
      }
    }
    #pragma unroll
    for (int ii = 0; ii < 4; ++ii)
      *(float4*)&smH[wv][g3][4*hh + 32*ii] = H4[ii];
  }
  __syncthreads();   // all waves' smH/smw/smJ visible block-wide

  // ---- phase D (block-wide, t<128): outv for all 4 points; pe_w2 rows read once ----
  if (t < 128){
    int c = t, g = c >> 4;
    float acc[4] = {0.f, 0.f, 0.f, 0.f};
    for (int i = 0; i < 32; ++i){
      float4 pw = *(const float4*)&pe_w2[c*128 + 4*i];
      #pragma unroll
      for (int pt = 0; pt < 4; ++pt){
        float4 h4 = *(const float4*)&smH[pt][g][4*i];
        acc[pt] = fmaf(pw.x, h4.x, acc[pt]);
        acc[pt] = fmaf(pw.y, h4.y, acc[pt]);
        acc[pt] = fmaf(pw.z, h4.z, acc[pt]);
        acc[pt] = fmaf(pw.w, h4.w, acc[pt]);
      }
    }
    #pragma unroll
    for (int pt = 0; pt < 4; ++pt){
      #pragma unroll
      for (int kk = 0; kk < 16; ++kk){
        int jj = smJ[pt][kk];
        float wgk = smw[pt][kk][g];
        acc[pt] = fmaf(wgk, vfT[((size_t)b*NPTS + jj)*CH + c], acc[pt]);
      }
      smOutv[pt][c] = acc[pt];
    }
  }
  __syncthreads();

  // ---- phase E (t<128): out[o][n0..n0+3] = bno(wo @ outv), float4 store ----
  if (t < 128){
    int o = t;
    float so = bno_g[o] / sqrtf(bno_v[o] + EPSN);
    float bo = bno_b[o] - bno_m[o] * so;
    float fa[4] = {0.f, 0.f, 0.f, 0.f};
    for (int i = 0; i < 32; ++i){
      float4 pw = *(const float4*)&wo[o*128 + 4*i];
      #pragma unroll
      for (int pt = 0; pt < 4; ++pt){
        float4 h4 = *(const float4*)&smOutv[pt][4*i];
        fa[pt] = fmaf(pw.x, h4.x, fa[pt]);
        fa[pt] = fmaf(pw.y, h4.y, fa[pt]);
        fa[pt] = fmaf(pw.z, h4.z, fa[pt]);
        fa[pt] = fmaf(pw.w, h4.w, fa[pt]);
      }
    }
    float4 st;
    st.x = fmaf(so, fa[0], bo);
    st.y = fmaf(so, fa[1], bo);
    st.z = fmaf(so, fa[2], bo);
    st.w = fmaf(so, fa[3], bo);
    *(float4*)&out[((size_t)b*CH + o)*NPTS + n0] = st;
  }
}

extern "C" void kernel_launch(void* const* d_in, const int* in_sizes, int n_in,
                              void* d_out, int out_size, void* d_ws, size_t ws_size,
                              hipStream_t stream){
  const float* x     = (const float*)d_in[0];
  const float* xyz   = (const float*)d_in[1];
  const float* wq    = (const float*)d_in[2];
  const float* bnq_g = (const float*)d_in[3];
  const float* bnq_b = (const float*)d_in[4];
  const float* bnq_m = (const float*)d_in[5];
  const float* bnq_v = (const float*)d_in[6];
  const float* wk    = (const float*)d_in[7];
  const float* bnk_g = (const float*)d_in[8];
  const float* bnk_b = (const float*)d_in[9];
  const float* bnk_m = (const float*)d_in[10];
  const float* bnk_v = (const float*)d_in[11];
  const float* wv    = (const float*)d_in[12];
  const float* pe_w1 = (const float*)d_in[13];
  const float* pe_g  = (const float*)d_in[14];
  const float* pe_b  = (const float*)d_in[15];
  const float* pe_m  = (const float*)d_in[16];
  const float* pe_v  = (const float*)d_in[17];
  const float* pe_w2 = (const float*)d_in[18];
  const float* we_w1 = (const float*)d_in[19];
  const float* we_g  = (const float*)d_in[20];
  const float* we_b  = (const float*)d_in[21];
  const float* we_m  = (const float*)d_in[22];
  const float* we_v  = (const float*)d_in[23];
  const float* we_w2 = (const float*)d_in[24];
  const float* wo    = (const float*)d_in[25];
  const float* bno_g = (const float*)d_in[26];
  const float* bno_b = (const float*)d_in[27];
  const float* bno_m = (const float*)d_in[28];
  const float* bno_v = (const float*)d_in[29];

  char* ws = (char*)d_ws;
  float*  wsA   = (float*)(ws + WS_A);
  float4* wsPW1 = (float4*)(ws + WS_PW1);
  float*  wsWE2 = (float*)(ws + WS_WE2);
  float4* pts   = (float4*)(ws + WS_PTS);
  float*  eqT   = (float*)(ws + WS_EQ);
  float*  ekT   = (float*)(ws + WS_EK);
  int*    idxw  = (int*)(ws + WS_IDX);
  float*  vfT   = (float*)(ws + WS_VFT);
  float*  outp  = (float*)d_out;

  k0_precomp<<<dim3(1), dim3(256), 0, stream>>>(we_w1, pe_w2, pe_w1, we_g, we_v,
                                                pe_g, pe_b, pe_m, pe_v, we_w2,
                                                wsA, wsPW1, wsWE2);
  k1_pts<<<dim3(64), dim3(256), 0, stream>>>(xyz, pts);
  // 3584 blocks = 512 groups x (3 k2-role + 4 k3-role)
  k23_fused<<<dim3(3584), dim3(256), K23_LDS, stream>>>(x, wq, wk, wv,
                                               bnq_g, bnq_b, bnq_m, bnq_v,
                                               bnk_g, bnk_b, bnk_m, bnk_v,
                                               we_w1, we_g, we_b, we_m, we_v,
                                               eqT, ekT, vfT, pts, idxw);
  k4_attn<<<dim3(BATCH*(NPTS/4)), dim3(256), 0, stream>>>(pts, eqT, ekT, idxw, vfT,
                                                wsA, wsPW1, wsWE2, pe_w2, wo,
                                                bno_g, bno_b, bno_m, bno_v, outp);
}